// Round 14
// baseline (116.926 us; speedup 1.0000x reference)
//
#include <hip/hip_runtime.h>
#include <math.h>
#include <stdint.h>

namespace {
constexpr int N = 8, C = 48, H = 96, W = 72;
constexpr int HW = H * W;        // 6912 = 144*48 = 54*128
constexpr int P = N * HW;        // 55296
constexpr float BN_EPS = 1e-5f;

constexpr int KSTEPS = 14;       // K = tap*48+c padded to 448
constexpr int PXB    = 48;       // pixels per fused block

// ws layout (BYTE offsets) — A-fragments fp16
constexpr int WS_ACONV = 0;                        // [ks14][lane64][8] f16
constexpr int ACONV_EL = KSTEPS * 64 * 8;          // 7168
constexpr int WS_ADEF  = WS_ACONV + ACONV_EL * 2;  // 14336; [ks14][mt3][lane64][8] f16
constexpr int ADEF_EL  = KSTEPS * 3 * 64 * 8;      // 21504
constexpr int WS_SC    = WS_ADEF + ADEF_EL * 2;    // 57344: f32[48]
constexpr int WS_BI    = WS_SC + 192;              // 57536: f32[48]
constexpr int WS_XT    = 57728;                    // fp16 NHWC x: [n][hw][48]

typedef __attribute__((ext_vector_type(8))) _Float16  half8;
typedef __attribute__((ext_vector_type(4))) float     f32x4;
typedef __attribute__((ext_vector_type(4))) unsigned  u32x4;
}

// ---------------------------------------------------------------------------
// transpose + prep: x NCHW f32 -> xT NHWC fp16 (128 px/block, 16B stores);
// first blocks also write MFMA A-fragments (fp16) + BN fold.
// ---------------------------------------------------------------------------
__global__ __launch_bounds__(256) void transpose_prep_kernel(
    const float* __restrict__ x,
    const float* __restrict__ tm_w, const float* __restrict__ tr_w,
    const float* __restrict__ mk_w, const float* __restrict__ dw,
    const float* __restrict__ gamma, const float* __restrict__ beta,
    const float* __restrict__ rmean, const float* __restrict__ rvar,
    unsigned char* __restrict__ wsb)
{
    __shared__ float tile[48][128];   // 24 KB
    int tid = threadIdx.x;
    int b   = blockIdx.x;
    int n   = b & 7;
    int hw0 = (b >> 3) * 128;         // HW = 54*128

#pragma unroll
    for (int it = 0; it < 24; ++it) {
        int c  = it * 2 + (tid >> 7);
        int px = tid & 127;
        tile[c][px] = x[((size_t)(n * C + c)) * HW + hw0 + px];
    }
    __syncthreads();

    {
        int px   = tid >> 1;
        int half = tid & 1;
        unsigned short* xt = (unsigned short*)(wsb + WS_XT);
        size_t base = ((size_t)(n * HW + hw0 + px)) * 48 + half * 24;
        unsigned pk[12];
#pragma unroll
        for (int k = 0; k < 12; ++k) {
            _Float16 h0 = (_Float16)tile[half * 24 + 2 * k][px];
            _Float16 h1 = (_Float16)tile[half * 24 + 2 * k + 1][px];
            pk[k] = (unsigned)__builtin_bit_cast(unsigned short, h0) |
                    ((unsigned)__builtin_bit_cast(unsigned short, h1) << 16);
        }
#pragma unroll
        for (int k = 0; k < 3; ++k)
            *(u32x4*)(xt + base + k * 8) =
                (u32x4){pk[4 * k], pk[4 * k + 1], pk[4 * k + 2], pk[4 * k + 3]};
    }

    // ---- prep piggyback ----
    int gtid = b * 256 + tid;
    if (gtid < ACONV_EL) {
        int i  = gtid & 7;
        int l  = (gtid >> 3) & 63;
        int ks = gtid >> 9;
        int o  = l & 15;
        int Kg = ks * 32 + ((l >> 4) * 8) + i;
        int t  = Kg / 48, c = Kg % 48;
        float v = 0.f;
        if (o < 15 && t < 9) {
            if (o < 4)      v = tm_w[(o * C + c) * 9 + t];
            else if (o < 6) v = tr_w[((o - 4) * C + c) * 9 + t];
            else            v = mk_w[((o - 6) * C + c) * 9 + t];
        }
        ((unsigned short*)(wsb + WS_ACONV))[gtid] =
            __builtin_bit_cast(unsigned short, (_Float16)v);
    }
    int t2 = gtid - ACONV_EL;
    if (t2 >= 0 && t2 < ADEF_EL) {
        int i  = t2 & 7;
        int l  = (t2 >> 3) & 63;
        int r2 = t2 >> 9;             // ks*3 + mt
        int mt = r2 % 3;
        int ks = r2 / 3;
        int o  = mt * 16 + (l & 15);
        int Kg = ks * 32 + ((l >> 4) * 8) + i;
        int t  = Kg / 48, c = Kg % 48;
        float v = (t < 9) ? dw[(o * C + c) * 9 + t] : 0.f;
        ((unsigned short*)(wsb + WS_ADEF))[t2] =
            __builtin_bit_cast(unsigned short, (_Float16)v);
    }
    if (gtid < C) {
        float sc = gamma[gtid] * rsqrtf(rvar[gtid] + BN_EPS);
        ((float*)(wsb + WS_SC))[gtid] = sc;
        ((float*)(wsb + WS_BI))[gtid] = beta[gtid] - rmean[gtid] * sc;
    }
}

// ---------------------------------------------------------------------------
// Fused kernel: 576 threads = 9 waves = 9 taps, 48 px/block.
// fp16 MFMA; dual accumulators (even/odd ks) halve the MFMA dep chain;
// residual x prefetched before the deform GEMM.
// ---------------------------------------------------------------------------
__global__ __launch_bounds__(576, 5) void fused_kernel(
    const float* __restrict__ x,
    const float* __restrict__ tm_b, const float* __restrict__ tr_b,
    const float* __restrict__ mk_b,
    const unsigned char* __restrict__ wsb,
    float* __restrict__ out)
{
    __shared__ __align__(16) unsigned char lds[PXB * 896 + 16 * PXB * 4];  // 46,080 B
    float* convout = (float*)(lds + PXB * 896);

    const int tid = threadIdx.x;
    const int l   = tid & 63;
    const int wv  = __builtin_amdgcn_readfirstlane(tid >> 6);   // 0..8 = tap

    const int b    = blockIdx.x;
    const int n    = b & 7;                 // XCD-aligned batch
    const int tile = b >> 3;                // 0..143
    const int hw   = tile * PXB + (l < PXB ? l : PXB - 1);
    const int ph   = hw / W;
    const int pw   = hw - ph * W;

    const unsigned short* xtn = (const unsigned short*)(wsb + WS_XT) + (size_t)n * HW * 48;
    const int swz = (l & 7) << 4;
    const int rowbase = l * 896 + wv * 96;

    // ---- zero the K-pad (logical bytes 864..895 of each row) once ----
    if (wv == 0 && l < PXB) {
        *(u32x4*)(lds + ((l * 896 + 864) ^ swz)) = (u32x4){0u, 0u, 0u, 0u};
        *(u32x4*)(lds + ((l * 896 + 880) ^ swz)) = (u32x4){0u, 0u, 0u, 0u};
    }

    // ---------------- conv staging: integer tap wv (pure fp16 copy) ----------------
    if (l < PXB) {
        int dy = wv / 3 - 1, dx = wv % 3 - 1;
        int hh = ph + dy, ww = pw + dx;
        bool v = ((unsigned)hh < (unsigned)H) && ((unsigned)ww < (unsigned)W);
        const unsigned char* src = (const unsigned char*)(xtn + (size_t)(v ? hh * W + ww : 0) * 48);
#pragma unroll
        for (int j = 0; j < 6; ++j) {
            u32x4 val = v ? *(const u32x4*)(src + j * 16) : (u32x4){0u, 0u, 0u, 0u};
            *(u32x4*)(lds + ((rowbase + j * 16) ^ swz)) = val;
        }
    }
    __syncthreads();   // ---- bar 1

    // ---------------- conv GEMM (waves 0-2, M=16 x N=48), dual acc ----------------
    if (wv < 3) {
        const _Float16* Ac = (const _Float16*)(wsb + WS_ACONV);
        f32x4 a0 = {0.f, 0.f, 0.f, 0.f}, a1 = {0.f, 0.f, 0.f, 0.f};
        int pxc = wv * 16 + (l & 15);
        int bbase = pxc * 896 + ((l >> 4) << 4);
#pragma unroll
        for (int ks = 0; ks < KSTEPS; ks += 2) {
            half8 b0 = *(const half8*)(lds + ((bbase + ks * 64) ^ swz));
            half8 f0 = *(const half8*)(Ac + (ks * 64 + l) * 8);
            a0 = __builtin_amdgcn_mfma_f32_16x16x32_f16(f0, b0, a0, 0, 0, 0);
            half8 b1 = *(const half8*)(lds + ((bbase + (ks + 1) * 64) ^ swz));
            half8 f1 = *(const half8*)(Ac + ((ks + 1) * 64 + l) * 8);
            a1 = __builtin_amdgcn_mfma_f32_16x16x32_f16(f1, b1, a1, 0, 0, 0);
        }
        int rowg = (l >> 4) * 4;
#pragma unroll
        for (int r = 0; r < 4; ++r)
            convout[(rowg + r) * PXB + pxc] = a0[r] + a1[r];
    }
    __syncthreads();   // ---- bar 2

    // ---------------- offsets + bilinear sample for (tap wv, px l) ----------------
    if (l < PXB) {
        float T0 = convout[0 * PXB + l] + tm_b[0];
        float T1 = convout[1 * PXB + l] + tm_b[1];
        float T2 = convout[2 * PXB + l] + tm_b[2];
        float T3 = convout[3 * PXB + l] + tm_b[3];
        float R0 = convout[4 * PXB + l] + tr_b[0];
        float R1 = convout[5 * PXB + l] + tr_b[1];
        float ry = (float)(wv / 3) - 1.f;
        float rx = (float)(wv % 3) - 1.f;
        float o_y = fmaf(T0, ry, fmaf(T1, rx, R0)) - ry;
        float o_x = fmaf(T2, ry, fmaf(T3, rx, R1)) - rx;
        float msk = convout[(6 + wv) * PXB + l] + mk_b[wv];

        float py  = (float)(ph + wv / 3 - 1) + o_y;
        float pxf = (float)(pw + wv % 3 - 1) + o_x;
        float y0f = floorf(py), x0f = floorf(pxf);
        float wy = py - y0f, wx = pxf - x0f;
        int y0 = (int)y0f, x0 = (int)x0f;
        int y1 = y0 + 1,  x1 = x0 + 1;
        bool vy0 = (unsigned)y0 < (unsigned)H;
        bool vy1 = (unsigned)y1 < (unsigned)H;
        bool vx0 = (unsigned)x0 < (unsigned)W;
        bool vx1 = (unsigned)x1 < (unsigned)W;
        int cy0 = min(max(y0, 0), H - 1) * W;
        int cy1 = min(max(y1, 0), H - 1) * W;
        int cx0 = min(max(x0, 0), W - 1);
        int cx1 = min(max(x1, 0), W - 1);
        float a00 = (vy0 && vx0) ? (1.f - wy) * (1.f - wx) * msk : 0.f;
        float a01 = (vy0 && vx1) ? (1.f - wy) * wx * msk         : 0.f;
        float a10 = (vy1 && vx0) ? wy * (1.f - wx) * msk         : 0.f;
        float a11 = (vy1 && vx1) ? wy * wx * msk                 : 0.f;

        _Float16 w00 = (_Float16)a00, w01 = (_Float16)a01;
        _Float16 w10 = (_Float16)a10, w11 = (_Float16)a11;

        const _Float16* r00 = (const _Float16*)(xtn + (size_t)(cy0 + cx0) * 48);
        const _Float16* r01 = (const _Float16*)(xtn + (size_t)(cy0 + cx1) * 48);
        const _Float16* r10 = (const _Float16*)(xtn + (size_t)(cy1 + cx0) * 48);
        const _Float16* r11 = (const _Float16*)(xtn + (size_t)(cy1 + cx1) * 48);

#pragma unroll
        for (int ch = 0; ch < 2; ++ch) {
            half8 c00[3], c01[3], c10[3], c11[3];
#pragma unroll
            for (int j = 0; j < 3; ++j) {
                int jj = ch * 3 + j;
                c00[j] = *(const half8*)(r00 + jj * 8);
                c01[j] = *(const half8*)(r01 + jj * 8);
                c10[j] = *(const half8*)(r10 + jj * 8);
                c11[j] = *(const half8*)(r11 + jj * 8);
            }
#pragma unroll
            for (int j = 0; j < 3; ++j) {
                int jj = ch * 3 + j;
                half8 s = c00[j] * w00 + c01[j] * w01 + c10[j] * w10 + c11[j] * w11;
                *(u32x4*)(lds + ((rowbase + jj * 16) ^ swz)) = __builtin_bit_cast(u32x4, s);
            }
        }
    }

    // ---------------- residual prefetch (independent of bar 3) ----------------
    const int mt = wv / 3, nt = wv % 3;
    const int pxc = nt * 16 + (l & 15);
    const int rowg = (l >> 4) * 4;
    const size_t abase = ((size_t)(n * C + mt * 16 + rowg)) * HW + tile * PXB + pxc;
    float xres[4];
#pragma unroll
    for (int r = 0; r < 4; ++r) xres[r] = x[abase + (size_t)r * HW];

    __syncthreads();   // ---- bar 3

    // ---------------- deform GEMM: 9 C-tiles, one per wave, dual acc ----------------
    {
        const _Float16* Ad = (const _Float16*)(wsb + WS_ADEF);
        const float* sc = (const float*)(wsb + WS_SC);
        const float* bi = (const float*)(wsb + WS_BI);

        int bbase = pxc * 896 + ((l >> 4) << 4);
        f32x4 a0 = {0.f, 0.f, 0.f, 0.f}, a1 = {0.f, 0.f, 0.f, 0.f};
#pragma unroll
        for (int ks = 0; ks < KSTEPS; ks += 2) {
            half8 b0 = *(const half8*)(lds + ((bbase + ks * 64) ^ swz));
            half8 f0 = *(const half8*)(Ad + ((ks * 3 + mt) * 64 + l) * 8);
            a0 = __builtin_amdgcn_mfma_f32_16x16x32_f16(f0, b0, a0, 0, 0, 0);
            half8 b1 = *(const half8*)(lds + ((bbase + (ks + 1) * 64) ^ swz));
            half8 f1 = *(const half8*)(Ad + (((ks + 1) * 3 + mt) * 64 + l) * 8);
            a1 = __builtin_amdgcn_mfma_f32_16x16x32_f16(f1, b1, a1, 0, 0, 0);
        }
#pragma unroll
        for (int r = 0; r < 4; ++r) {
            int o = mt * 16 + rowg + r;
            float v = fmaf(a0[r] + a1[r], sc[o], bi[o]) + xres[r];
            out[abase + (size_t)r * HW] = fmaxf(v, 0.f);
        }
    }
}

// ---------------------------------------------------------------------------
extern "C" void kernel_launch(void* const* d_in, const int* in_sizes, int n_in,
                              void* d_out, int out_size, void* d_ws, size_t ws_size,
                              hipStream_t stream)
{
    const float* x     = (const float*)d_in[0];
    const float* tm_w  = (const float*)d_in[1];
    const float* tm_b  = (const float*)d_in[2];
    const float* tr_w  = (const float*)d_in[3];
    const float* tr_b  = (const float*)d_in[4];
    const float* mk_w  = (const float*)d_in[5];
    const float* mk_b  = (const float*)d_in[6];
    const float* dw    = (const float*)d_in[7];
    const float* gamma = (const float*)d_in[8];
    const float* beta  = (const float*)d_in[9];
    const float* rmean = (const float*)d_in[10];
    const float* rvar  = (const float*)d_in[11];
    float* out = (float*)d_out;
    unsigned char* wsb = (unsigned char*)d_ws;

    hipLaunchKernelGGL(transpose_prep_kernel, dim3(P / 128), dim3(256), 0, stream,
                       x, tm_w, tr_w, mk_w, dw, gamma, beta, rmean, rvar, wsb);
    hipLaunchKernelGGL(fused_kernel, dim3(P / PXB), dim3(576), 0, stream,
                       x, tm_b, tr_b, mk_b, wsb, out);
}